// Round 4
// baseline (312.987 us; speedup 1.0000x reference)
//
#include <hip/hip_runtime.h>
#include <stdint.h>

#define DEV __device__ __forceinline__

typedef __attribute__((ext_vector_type(8))) __bf16 bf16x8;
typedef __attribute__((ext_vector_type(4))) float floatx4;

DEV float bf2f(unsigned short u) {
  union { unsigned int i; float f; } x; x.i = ((unsigned int)u) << 16; return x.f;
}
DEV unsigned int f2bf(float f) {
  union { float f; unsigned int i; } x; x.f = f;
  unsigned int r = x.i + 0x7FFFu + ((x.i >> 16) & 1u);
  return r >> 16;
}
DEV void gl2lds16(const unsigned short* g, unsigned short* l) {
  __builtin_amdgcn_global_load_lds(
      (const __attribute__((address_space(1))) unsigned int*)g,
      (__attribute__((address_space(3))) unsigned int*)l, 16, 0, 0);
}
DEV floatx4 zero4() { floatx4 z; z[0]=0.f; z[1]=0.f; z[2]=0.f; z[3]=0.f; return z; }

// ---------------- transposes: Wt[n][k] = bf16(W[k][n]), all 4 weights -------
__global__ void cca_transpose_k(const float* __restrict__ W0,
                                const float* __restrict__ W1,
                                const float* __restrict__ W2,
                                const float* __restrict__ W3,
                                unsigned short* __restrict__ D0,
                                unsigned short* __restrict__ D1,
                                unsigned short* __restrict__ D2,
                                unsigned short* __restrict__ D3) {
  __shared__ float tile[64][65];
  const float* W; unsigned short* Wt;
  switch (blockIdx.z) {
    case 0: W = W0; Wt = D0; break;
    case 1: W = W1; Wt = D1; break;
    case 2: W = W2; Wt = D2; break;
    default: W = W3; Wt = D3; break;
  }
  const int K = 1024, N = 1024;
  int k0 = blockIdx.x * 64, n0 = blockIdx.y * 64;
  int t = threadIdx.x;
  int c = t & 63, r4 = t >> 6;
#pragma unroll
  for (int it = 0; it < 16; ++it) {
    int r = it * 4 + r4;
    tile[r][c] = W[(size_t)(k0 + r) * N + n0 + c];
  }
  __syncthreads();
#pragma unroll
  for (int it = 0; it < 16; ++it) {
    int r = it * 4 + r4;
    Wt[(size_t)(n0 + r) * K + k0 + c] = (unsigned short)f2bf(tile[c][r]);
  }
}

// -------- prep: blocks [0,16384)=e f32->bf16; [16384,20480)=rmsnorm;
//                [20480,20732)=copy head rows (out rows s<63 = h) ------------
__global__ void cca_prep_k(const float* __restrict__ e,
                           unsigned short* __restrict__ eb,
                           const float* __restrict__ h,
                           const float* __restrict__ g,
                           unsigned short* __restrict__ hn,
                           float* __restrict__ out) {
  int blk = blockIdx.x;
  int t = threadIdx.x;
  if (blk < 16384) {                      // f32 -> bf16, 1024 elems/block
    int i = blk * 256 + t;
    float4 v = ((const float4*)e)[i];
    uint2 o;
    o.x = f2bf(v.x) | (f2bf(v.y) << 16);
    o.y = f2bf(v.z) | (f2bf(v.w) << 16);
    ((uint2*)eb)[i] = o;
    return;
  }
  if (blk < 20480) {                      // rmsnorm row
    int row = blk - 16384;                // 0..4095
    int b = row >> 10, p = row & 1023;
    unsigned short* dst = hn + (size_t)row * 1024;
    if (p >= 961) {
      uint2 z; z.x = 0u; z.y = 0u;
      ((uint2*)dst)[t] = z;
      return;
    }
    const float* src = h + ((size_t)(b << 10) + p + 63) * 1024;
    float4 v = ((const float4*)src)[t];
    float ss = v.x*v.x + v.y*v.y + v.z*v.z + v.w*v.w;
#pragma unroll
    for (int m = 32; m > 0; m >>= 1) ss += __shfl_down(ss, m);
    __shared__ float wsum[4];
    int lane = t & 63, wv = t >> 6;
    if (lane == 0) wsum[wv] = ss;
    __syncthreads();
    float tot = wsum[0] + wsum[1] + wsum[2] + wsum[3];
    float r = rsqrtf(tot * (1.0f / 1024.0f) + 1e-8f);
    float4 gv = ((const float4*)g)[t];
    uint2 outp;
    outp.x = f2bf(v.x * gv.x * r) | (f2bf(v.y * gv.y * r) << 16);
    outp.y = f2bf(v.z * gv.z * r) | (f2bf(v.w * gv.w * r) << 16);
    ((uint2*)dst)[t] = outp;
    return;
  }
  {                                        // head copy, one float4/thread
    int idx = (blk - 20480) * 256 + t;
    const int n4 = 4 * 63 * 1024 / 4;      // 64512
    if (idx < n4) {
      int e4 = idx * 4;
      int b = e4 / (63 * 1024);
      int r = e4 - b * (63 * 1024);
      size_t off = (size_t)b * 1024 * 1024 + (size_t)r;
      *(float4*)(out + off) = *(const float4*)(h + off);
    }
  }
}

// ---------------- GEMM: C[M][N] = A[M][K] @ Bt[N][K]^T + bias ---------------
// XOR-swizzled LDS K-chunks: phys_chunk = logical_chunk ^ ((row>>1)&3)
// MODE 0: bf16 store to C, bias = (n<1024? bias1[n] : bias2[n-1024])
// MODE 1: f32 store, out row shift +63, skip p>=961, add f32 residual, bias1
template <int MODE>
__launch_bounds__(256, 2)
__global__ void cca_gemm_k(const unsigned short* __restrict__ A,
                           const unsigned short* __restrict__ Bt,
                           const float* __restrict__ bias1,
                           const float* __restrict__ bias2,
                           const float* __restrict__ resid,
                           void* __restrict__ Cout,
                           int M, int N, int K) {
  __shared__ unsigned short Ash[128 * 32];
  __shared__ unsigned short Bsh[128 * 32];
  int tM = blockIdx.x * 128, tN = blockIdx.y * 128;
  int t = threadIdx.x, lane = t & 63, wv = t >> 6;
  int wm = wv >> 1, wn = wv & 1;
  int l15 = lane & 15, quad = lane >> 4;
  int arow = lane >> 2, achk = lane & 3;        // staging: 4 lanes / 64B row
  int gchk = achk ^ ((arow >> 1) & 3);          // swizzled source chunk
  int rchk = quad ^ ((l15 >> 1) & 3);           // swizzled fragment chunk
  floatx4 acc[4][4];
#pragma unroll
  for (int i = 0; i < 4; ++i)
#pragma unroll
    for (int j = 0; j < 4; ++j) acc[i][j] = zero4();

  for (int k0 = 0; k0 < K; k0 += 32) {
    __syncthreads();
#pragma unroll
    for (int ii = 0; ii < 2; ++ii) {
      int seg = wv + ii * 4;                    // 0..7, 16 rows each
      int row = seg * 16 + arow;
      gl2lds16(A + (size_t)(tM + row) * K + k0 + gchk * 8, Ash + seg * 512);
      gl2lds16(Bt + (size_t)(tN + row) * K + k0 + gchk * 8, Bsh + seg * 512);
    }
    __syncthreads();
    bf16x8 af[4], bfv[4];
#pragma unroll
    for (int mt = 0; mt < 4; ++mt)
      af[mt] = *(const bf16x8*)&Ash[(wm * 64 + mt * 16 + l15) * 32 + rchk * 8];
#pragma unroll
    for (int nt = 0; nt < 4; ++nt)
      bfv[nt] = *(const bf16x8*)&Bsh[(wn * 64 + nt * 16 + l15) * 32 + rchk * 8];
#pragma unroll
    for (int mt = 0; mt < 4; ++mt)
#pragma unroll
      for (int nt = 0; nt < 4; ++nt)
        acc[mt][nt] = __builtin_amdgcn_mfma_f32_16x16x32_bf16(af[mt], bfv[nt], acc[mt][nt], 0, 0, 0);
  }

#pragma unroll
  for (int mt = 0; mt < 4; ++mt) {
    int mrow = tM + wm * 64 + mt * 16 + quad * 4;
#pragma unroll
    for (int nt = 0; nt < 4; ++nt) {
      int ncol = tN + wn * 64 + nt * 16 + l15;
      float bs;
      if (MODE == 0) {
        bs = (bias2 != nullptr && ncol >= 1024) ? bias2[ncol - 1024] : bias1[ncol];
      } else {
        bs = bias1[ncol];
      }
#pragma unroll
      for (int r = 0; r < 4; ++r) {
        int m = mrow + r;
        float v = acc[mt][nt][r] + bs;
        if (MODE == 0) {
          ((unsigned short*)Cout)[(size_t)m * N + ncol] = (unsigned short)f2bf(v);
        } else {
          int p = m & 1023;
          if (p < 961) {
            size_t o = (size_t)(m + 63) * 1024 + (size_t)ncol;
            ((float*)Cout)[o] = v + resid[o];
          }
        }
      }
    }
  }
}

// ------- V transpose: VTb[bch][d][key], stride 256, XOR-swizzled 16B units --
// phys layout elem index: bch*16384 + d*256 + (u ^ (d&7))*8 + (j&7), u = j>>3
__global__ void cca_vt_k(const unsigned short* __restrict__ KV,  // [16384][2048]
                         unsigned short* __restrict__ VTb) {
  __shared__ unsigned short tile[256 * 66];    // [key][d], padded
  int bch = blockIdx.x;
  int hh = bch & 15, c = (bch >> 4) & 15, b = bch >> 8;
  size_t kvbase = (size_t)b * 4096 + (size_t)c * 256;
  int t = threadIdx.x;
  // read V block: 256 keys x 64 d, coalesced uint2 loads
#pragma unroll
  for (int it = 0; it < 16; ++it) {
    int flat = it * 256 + t;          // 0..4095 uint2
    int row = flat >> 4, cu = flat & 15;
    uint2 v = *(const uint2*)(KV + (kvbase + row) * 2048 + 1024 + hh * 64 + cu * 4);
    int d0 = cu * 4;
    tile[row * 66 + d0 + 0] = (unsigned short)(v.x & 0xffff);
    tile[row * 66 + d0 + 1] = (unsigned short)(v.x >> 16);
    tile[row * 66 + d0 + 2] = (unsigned short)(v.y & 0xffff);
    tile[row * 66 + d0 + 3] = (unsigned short)(v.y >> 16);
  }
  __syncthreads();
  // write transposed+swizzled: 4 keys per uint2
  unsigned short* dst = VTb + (size_t)bch * 16384;
#pragma unroll
  for (int it = 0; it < 16; ++it) {
    int flat = it * 256 + t;          // 0..4095 uint2
    int d = flat >> 6, ju = flat & 63;
    int j = ju * 4;
    unsigned int lo = (unsigned int)tile[(j + 0) * 66 + d] |
                      ((unsigned int)tile[(j + 1) * 66 + d] << 16);
    unsigned int hi = (unsigned int)tile[(j + 2) * 66 + d] |
                      ((unsigned int)tile[(j + 3) * 66 + d] << 16);
    int u = j >> 3, joff = j & 7;
    int phys = d * 256 + ((u ^ (d & 7)) << 3) + joff;
    uint2 o; o.x = lo; o.y = hi;
    *(uint2*)(dst + phys) = o;
  }
}

// ---------------- attention: one block per (b, c, head), 2 blocks/CU --------
__launch_bounds__(256, 2)
__global__ void cca_attn_k(const unsigned short* __restrict__ Q,   // [4096][1024]
                           const unsigned short* __restrict__ KV,  // [16384][2048]
                           const unsigned short* __restrict__ VTb, // per-bch 64x256 swz
                           unsigned short* __restrict__ O) {       // [4096][1024]
  // Qsh (8K) + Ksh (32K) staged first; Psh (33.8K) aliases them after S-MFMA.
  __shared__ unsigned short smemA[64 * 64 + 256 * 64];
  __shared__ unsigned short VTlds[64 * 256];  // swizzled, staged via gl2lds
  unsigned short* Qsh = smemA;
  unsigned short* Ksh = smemA + 64 * 64;
  unsigned short* Psh = smemA;                // alias (post-barrier)
  int bch = blockIdx.x;
  int hh = bch & 15, c = (bch >> 4) & 15, b = bch >> 8;
  int t = threadIdx.x, lane = t & 63, wv = t >> 6;
  int l15 = lane & 15, quad = lane >> 4;
  size_t qbase = (size_t)b * 1024 + (size_t)c * 64;
  size_t kvbase = (size_t)b * 4096 + (size_t)c * 256;
  int hoff = hh * 64;

  // stage Q (8KB), K (32KB), VT (32KB) via async global->LDS, 16B/lane
  {
    int rowi = lane >> 3, chk = lane & 7;  // 8 lanes per 128B row
#pragma unroll
    for (int ii = 0; ii < 2; ++ii) {
      int seg = wv + ii * 4;
      int row = seg * 8 + rowi;
      gl2lds16(Q + (qbase + row) * 1024 + hoff + chk * 8, Qsh + seg * 512);
    }
#pragma unroll
    for (int ii = 0; ii < 8; ++ii) {
      int seg = wv + ii * 4;
      int row = seg * 8 + rowi;
      gl2lds16(KV + (kvbase + row) * 2048 + hoff + chk * 8, Ksh + seg * 512);
    }
    const unsigned short* vsrc = VTb + (size_t)bch * 16384;
#pragma unroll
    for (int ii = 0; ii < 8; ++ii) {
      int seg = wv + ii * 4;               // 0..31, 512 elems each
      gl2lds16(vsrc + seg * 512 + lane * 8, VTlds + seg * 512);
    }
  }
  __syncthreads();

  // S = Q K^T : wave wv owns q-rows wv*16..+15, full 256 keys
  floatx4 st[16];
#pragma unroll
  for (int i = 0; i < 16; ++i) st[i] = zero4();
  bf16x8 a0 = *(const bf16x8*)&Qsh[(wv * 16 + l15) * 64 + quad * 8];
  bf16x8 a1 = *(const bf16x8*)&Qsh[(wv * 16 + l15) * 64 + 32 + quad * 8];
#pragma unroll
  for (int kt = 0; kt < 16; ++kt) {
    bf16x8 b0 = *(const bf16x8*)&Ksh[(kt * 16 + l15) * 64 + quad * 8];
    bf16x8 b1 = *(const bf16x8*)&Ksh[(kt * 16 + l15) * 64 + 32 + quad * 8];
    st[kt] = __builtin_amdgcn_mfma_f32_16x16x32_bf16(a0, b0, st[kt], 0, 0, 0);
    st[kt] = __builtin_amdgcn_mfma_f32_16x16x32_bf16(a1, b1, st[kt], 0, 0, 0);
  }
  __syncthreads();   // all waves done reading Qsh/Ksh; Psh may now alias them

  // softmax over 256 keys; row i's values live in the 16 lanes of its quad
  const float scale = 0.125f;  // 1/sqrt(64)
#pragma unroll
  for (int r = 0; r < 4; ++r) {
    float mx = -1e30f;
#pragma unroll
    for (int kt = 0; kt < 16; ++kt) mx = fmaxf(mx, st[kt][r]);
    mx = fmaxf(mx, __shfl_xor(mx, 1));
    mx = fmaxf(mx, __shfl_xor(mx, 2));
    mx = fmaxf(mx, __shfl_xor(mx, 4));
    mx = fmaxf(mx, __shfl_xor(mx, 8));
    float sum = 0.f;
#pragma unroll
    for (int kt = 0; kt < 16; ++kt) {
      float e = __expf((st[kt][r] - mx) * scale);
      st[kt][r] = e;
      sum += e;
    }
    sum += __shfl_xor(sum, 1);
    sum += __shfl_xor(sum, 2);
    sum += __shfl_xor(sum, 4);
    sum += __shfl_xor(sum, 8);
    float inv = 1.0f / sum;
    int prow = wv * 16 + quad * 4 + r;
#pragma unroll
    for (int kt = 0; kt < 16; ++kt)
      Psh[prow * 264 + kt * 16 + l15] = (unsigned short)f2bf(st[kt][r] * inv);
  }
  // wave-private Psh rows: in-order LDS per wave, no barrier needed

  // O = P @ V  (VT fragment reads use the XOR swizzle: unit ^ (row&7))
  floatx4 ot[4];
#pragma unroll
  for (int nt = 0; nt < 4; ++nt) ot[nt] = zero4();
#pragma unroll
  for (int kt2 = 0; kt2 < 8; ++kt2) {
    bf16x8 ap = *(const bf16x8*)&Psh[(wv * 16 + l15) * 264 + kt2 * 32 + quad * 8];
#pragma unroll
    for (int nt = 0; nt < 4; ++nt) {
      int vrow = nt * 16 + l15;
      int u = kt2 * 4 + quad;
      bf16x8 bv8 = *(const bf16x8*)&VTlds[vrow * 256 + ((u ^ (vrow & 7)) << 3)];
      ot[nt] = __builtin_amdgcn_mfma_f32_16x16x32_bf16(ap, bv8, ot[nt], 0, 0, 0);
    }
  }
#pragma unroll
  for (int nt = 0; nt < 4; ++nt) {
#pragma unroll
    for (int r = 0; r < 4; ++r) {
      int i = wv * 16 + quad * 4 + r;
      int dcol = hoff + nt * 16 + l15;
      O[(qbase + i) * 1024 + dcol] = (unsigned short)f2bf(ot[nt][r]);
    }
  }
}

extern "C" void kernel_launch(void* const* d_in, const int* in_sizes, int n_in,
                              void* d_out, int out_size, void* d_ws, size_t ws_size,
                              hipStream_t stream) {
  const float* h  = (const float*)d_in[0];
  const float* e  = (const float*)d_in[1];
  const float* g  = (const float*)d_in[2];
  const float* Wq = (const float*)d_in[3];
  const float* bq = (const float*)d_in[4];
  const float* Wk = (const float*)d_in[5];
  const float* bk = (const float*)d_in[6];
  const float* Wv = (const float*)d_in[7];
  const float* bv = (const float*)d_in[8];
  const float* Wo = (const float*)d_in[9];
  const float* bo = (const float*)d_in[10];
  float* out = (float*)d_out;

  unsigned short* ws   = (unsigned short*)d_ws;
  unsigned short* hn   = ws;                                   // 4096*1024
  unsigned short* WqT  = hn   + (size_t)4096 * 1024;           // 1024*1024
  unsigned short* WkvT = WqT  + (size_t)1024 * 1024;           // 2048*1024
  unsigned short* WoT  = WkvT + (size_t)2048 * 1024;           // 1024*1024
  unsigned short* Qb   = WoT  + (size_t)1024 * 1024;           // 4096*1024
  unsigned short* KVb  = Qb   + (size_t)4096 * 1024;           // 16384*2048
  unsigned short* Ob   = KVb  + (size_t)16384 * 2048;          // 4096*1024
  unsigned short* eb   = Ob   + (size_t)4096 * 1024;           // 16384*1024
  unsigned short* VTb  = eb;   // alias: eb dead after KV GEMM, same size

  cca_transpose_k<<<dim3(16, 16, 4), 256, 0, stream>>>(
      Wq, Wk, Wv, Wo, WqT, WkvT, WkvT + (size_t)1024 * 1024, WoT);

  cca_prep_k<<<20732, 256, 0, stream>>>(e, eb, h, g, hn, out);

  cca_gemm_k<0><<<dim3(32, 8), 256, 0, stream>>>(hn, WqT, bq, nullptr, nullptr,
                                                 (void*)Qb, 4096, 1024, 1024);
  cca_gemm_k<0><<<dim3(128, 16), 256, 0, stream>>>(eb, WkvT, bk, bv, nullptr,
                                                   (void*)KVb, 16384, 2048, 1024);

  cca_vt_k<<<1024, 256, 0, stream>>>(KVb, VTb);

  cca_attn_k<<<1024, 256, 0, stream>>>(Qb, KVb, VTb, Ob);

  cca_gemm_k<1><<<dim3(32, 8), 256, 0, stream>>>(Ob, WoT, bo, nullptr, h,
                                                 (void*)out, 4096, 1024, 1024);
}

// Round 5
// 275.137 us; speedup vs baseline: 1.1376x; 1.1376x over previous
//
#include <hip/hip_runtime.h>
#include <stdint.h>

#define DEV __device__ __forceinline__

typedef __attribute__((ext_vector_type(8))) __bf16 bf16x8;
typedef __attribute__((ext_vector_type(4))) float floatx4;

DEV unsigned int f2bf(float f) {
  union { float f; unsigned int i; } x; x.f = f;
  unsigned int r = x.i + 0x7FFFu + ((x.i >> 16) & 1u);
  return r >> 16;
}
DEV void gl2lds16(const unsigned short* g, unsigned short* l) {
  __builtin_amdgcn_global_load_lds(
      (const __attribute__((address_space(1))) unsigned int*)g,
      (__attribute__((address_space(3))) unsigned int*)l, 16, 0, 0);
}
DEV floatx4 zero4() { floatx4 z; z[0]=0.f; z[1]=0.f; z[2]=0.f; z[3]=0.f; return z; }

// ---- merged prep: [0,1024) weight transposes; [1024,17408) e f32->bf16;
//      [17408,21504) rmsnorm; [21504,21756) head-row copy ---------------------
__global__ void cca_prep_k(const float* __restrict__ W0, const float* __restrict__ W1,
                           const float* __restrict__ W2, const float* __restrict__ W3,
                           unsigned short* __restrict__ D0, unsigned short* __restrict__ D1,
                           unsigned short* __restrict__ D2, unsigned short* __restrict__ D3,
                           const float* __restrict__ e, unsigned short* __restrict__ eb,
                           const float* __restrict__ h, const float* __restrict__ g,
                           unsigned short* __restrict__ hn, float* __restrict__ out) {
  __shared__ float tile[64][65];
  int blk = blockIdx.x;
  int t = threadIdx.x;
  if (blk < 1024) {                       // weight transpose, 64x64 tile
    const float* W; unsigned short* Wt;
    switch (blk >> 8) {
      case 0: W = W0; Wt = D0; break;
      case 1: W = W1; Wt = D1; break;
      case 2: W = W2; Wt = D2; break;
      default: W = W3; Wt = D3; break;
    }
    int k0 = (blk & 15) * 64, n0 = ((blk >> 4) & 15) * 64;
    int c = t & 63, r4 = t >> 6;
#pragma unroll
    for (int it = 0; it < 16; ++it) {
      int r = it * 4 + r4;
      tile[r][c] = W[(size_t)(k0 + r) * 1024 + n0 + c];
    }
    __syncthreads();
#pragma unroll
    for (int it = 0; it < 16; ++it) {
      int r = it * 4 + r4;
      Wt[(size_t)(n0 + r) * 1024 + k0 + c] = (unsigned short)f2bf(tile[c][r]);
    }
    return;
  }
  if (blk < 17408) {                      // e f32 -> bf16, 1024 elems/block
    int i = (blk - 1024) * 256 + t;
    float4 v = ((const float4*)e)[i];
    uint2 o;
    o.x = f2bf(v.x) | (f2bf(v.y) << 16);
    o.y = f2bf(v.z) | (f2bf(v.w) << 16);
    ((uint2*)eb)[i] = o;
    return;
  }
  if (blk < 21504) {                      // rmsnorm row
    int row = blk - 17408;                // 0..4095
    int b = row >> 10, p = row & 1023;
    unsigned short* dst = hn + (size_t)row * 1024;
    if (p >= 961) {
      uint2 z; z.x = 0u; z.y = 0u;
      ((uint2*)dst)[t] = z;
      return;
    }
    const float* src = h + ((size_t)(b << 10) + p + 63) * 1024;
    float4 v = ((const float4*)src)[t];
    float ss = v.x*v.x + v.y*v.y + v.z*v.z + v.w*v.w;
#pragma unroll
    for (int m = 32; m > 0; m >>= 1) ss += __shfl_down(ss, m);
    __shared__ float wsum[4];
    int lane = t & 63, wv = t >> 6;
    if (lane == 0) wsum[wv] = ss;
    __syncthreads();
    float tot = wsum[0] + wsum[1] + wsum[2] + wsum[3];
    float r = rsqrtf(tot * (1.0f / 1024.0f) + 1e-8f);
    float4 gv = ((const float4*)g)[t];
    uint2 outp;
    outp.x = f2bf(v.x * gv.x * r) | (f2bf(v.y * gv.y * r) << 16);
    outp.y = f2bf(v.z * gv.z * r) | (f2bf(v.w * gv.w * r) << 16);
    ((uint2*)dst)[t] = outp;
    return;
  }
  {                                        // head copy, one float4/thread
    int idx = (blk - 21504) * 256 + t;
    const int n4 = 4 * 63 * 1024 / 4;      // 64512
    if (idx < n4) {
      int e4 = idx * 4;
      int b = e4 / (63 * 1024);
      int r = e4 - b * (63 * 1024);
      size_t off = (size_t)b * 1024 * 1024 + (size_t)r;
      *(float4*)(out + off) = *(const float4*)(h + off);
    }
  }
}

// ---- merged QKV GEMM: blocks [0,2048) = KV (M=16384,N=2048); [2048,2304) = Q
//      128x128 tile, BK=64, 3-bit XOR unit swizzle. bf16 out + bias ----------
__launch_bounds__(256, 2)
__global__ void cca_gemmQKV_k(const unsigned short* __restrict__ eb,
                              const unsigned short* __restrict__ WkvT,
                              const float* __restrict__ bk,
                              const float* __restrict__ bv,
                              unsigned short* __restrict__ KVb,
                              const unsigned short* __restrict__ hn,
                              const unsigned short* __restrict__ WqT,
                              const float* __restrict__ bq,
                              unsigned short* __restrict__ Qb) {
  __shared__ unsigned short Ash[128 * 64];
  __shared__ unsigned short Bsh[128 * 64];
  int blk = blockIdx.x;
  const unsigned short *A, *Bt; const float *b1, *b2; unsigned short* C;
  int N, tM, tN;
  if (blk < 2048) {
    A = eb; Bt = WkvT; b1 = bk; b2 = bv; C = KVb; N = 2048;
    tM = (blk & 127) * 128; tN = (blk >> 7) * 128;
  } else {
    int q = blk - 2048;
    A = hn; Bt = WqT; b1 = bq; b2 = nullptr; C = Qb; N = 1024;
    tM = (q & 31) * 128; tN = (q >> 5) * 128;
  }
  int t = threadIdx.x, lane = t & 63, wv = t >> 6;
  int wm = wv >> 1, wn = wv & 1;
  int l15 = lane & 15, quad = lane >> 4;
  int arow = lane >> 3, achk = lane & 7;     // staging: 8 lanes / 128B row
  int gchk = achk ^ arow;                    // 3-bit XOR swizzled source unit
  floatx4 acc[4][4];
#pragma unroll
  for (int i = 0; i < 4; ++i)
#pragma unroll
    for (int j = 0; j < 4; ++j) acc[i][j] = zero4();

  for (int k0 = 0; k0 < 1024; k0 += 64) {
    __syncthreads();
#pragma unroll
    for (int ii = 0; ii < 4; ++ii) {
      int seg = ii * 4 + wv;                 // 0..15, 8 rows each
      int row = seg * 8 + arow;
      gl2lds16(A + (size_t)(tM + row) * 1024 + k0 + gchk * 8, Ash + seg * 512);
      gl2lds16(Bt + (size_t)(tN + row) * 1024 + k0 + gchk * 8, Bsh + seg * 512);
    }
    __syncthreads();
#pragma unroll
    for (int h = 0; h < 2; ++h) {
      int u = (h << 2) | quad;
      bf16x8 af[4], bfv[4];
#pragma unroll
      for (int mt = 0; mt < 4; ++mt) {
        int r = wm * 64 + mt * 16 + l15;
        af[mt] = *(const bf16x8*)&Ash[r * 64 + ((u ^ (l15 & 7)) << 3)];
      }
#pragma unroll
      for (int nt = 0; nt < 4; ++nt) {
        int r = wn * 64 + nt * 16 + l15;
        bfv[nt] = *(const bf16x8*)&Bsh[r * 64 + ((u ^ (l15 & 7)) << 3)];
      }
#pragma unroll
      for (int mt = 0; mt < 4; ++mt)
#pragma unroll
        for (int nt = 0; nt < 4; ++nt)
          acc[mt][nt] = __builtin_amdgcn_mfma_f32_16x16x32_bf16(af[mt], bfv[nt], acc[mt][nt], 0, 0, 0);
    }
  }

#pragma unroll
  for (int mt = 0; mt < 4; ++mt) {
    int mrow = tM + wm * 64 + mt * 16 + quad * 4;
#pragma unroll
    for (int nt = 0; nt < 4; ++nt) {
      int ncol = tN + wn * 64 + nt * 16 + l15;
      float bs = (b2 != nullptr && ncol >= 1024) ? b2[ncol - 1024] : b1[ncol];
#pragma unroll
      for (int r = 0; r < 4; ++r) {
        int m = mrow + r;
        C[(size_t)m * N + ncol] = (unsigned short)f2bf(acc[mt][nt][r] + bs);
      }
    }
  }
}

// ---- O-proj GEMM: 128x64 tile, BK=64; f32 out, +63 row shift, +residual ----
__launch_bounds__(256, 2)
__global__ void cca_gemmO_k(const unsigned short* __restrict__ A,   // Ob bf16
                            const unsigned short* __restrict__ Bt,  // WoT bf16
                            const float* __restrict__ bias,
                            const float* __restrict__ resid,
                            float* __restrict__ out) {
  __shared__ unsigned short Ash[128 * 64];
  __shared__ unsigned short Bsh[64 * 64];
  int tM = blockIdx.x * 128, tN = blockIdx.y * 64;
  int t = threadIdx.x, lane = t & 63, wv = t >> 6;
  int wm = wv >> 1, wn = wv & 1;
  int l15 = lane & 15, quad = lane >> 4;
  int arow = lane >> 3, achk = lane & 7;
  int gchk = achk ^ arow;
  floatx4 acc[4][2];
#pragma unroll
  for (int i = 0; i < 4; ++i)
#pragma unroll
    for (int j = 0; j < 2; ++j) acc[i][j] = zero4();

  for (int k0 = 0; k0 < 1024; k0 += 64) {
    __syncthreads();
#pragma unroll
    for (int ii = 0; ii < 4; ++ii) {
      int seg = ii * 4 + wv;
      int row = seg * 8 + arow;
      gl2lds16(A + (size_t)(tM + row) * 1024 + k0 + gchk * 8, Ash + seg * 512);
    }
#pragma unroll
    for (int ii = 0; ii < 2; ++ii) {
      int seg = ii * 4 + wv;                 // 0..7, 8 rows each
      int row = seg * 8 + arow;
      gl2lds16(Bt + (size_t)(tN + row) * 1024 + k0 + gchk * 8, Bsh + seg * 512);
    }
    __syncthreads();
#pragma unroll
    for (int h = 0; h < 2; ++h) {
      int u = (h << 2) | quad;
      bf16x8 af[4], bfv[2];
#pragma unroll
      for (int mt = 0; mt < 4; ++mt) {
        int r = wm * 64 + mt * 16 + l15;
        af[mt] = *(const bf16x8*)&Ash[r * 64 + ((u ^ (l15 & 7)) << 3)];
      }
#pragma unroll
      for (int nt = 0; nt < 2; ++nt) {
        int r = wn * 32 + nt * 16 + l15;
        bfv[nt] = *(const bf16x8*)&Bsh[r * 64 + ((u ^ (l15 & 7)) << 3)];
      }
#pragma unroll
      for (int mt = 0; mt < 4; ++mt)
#pragma unroll
        for (int nt = 0; nt < 2; ++nt)
          acc[mt][nt] = __builtin_amdgcn_mfma_f32_16x16x32_bf16(af[mt], bfv[nt], acc[mt][nt], 0, 0, 0);
    }
  }

#pragma unroll
  for (int mt = 0; mt < 4; ++mt) {
    int mrow = tM + wm * 64 + mt * 16 + quad * 4;
#pragma unroll
    for (int nt = 0; nt < 2; ++nt) {
      int ncol = tN + wn * 32 + nt * 16 + l15;
      float bs = bias[ncol];
#pragma unroll
      for (int r = 0; r < 4; ++r) {
        int m = mrow + r;
        int p = m & 1023;
        if (p < 961) {
          size_t o = (size_t)(m + 63) * 1024 + (size_t)ncol;
          out[o] = acc[mt][nt][r] + bs + resid[o];
        }
      }
    }
  }
}

// ------- V transpose: VTb[bch][d][key], stride 256, XOR-swizzled 16B units --
// phys elem: bch*16384 + d*256 + ((u ^ (d&7))<<3) + (j&7), u = j>>3
__global__ void cca_vt_k(const unsigned short* __restrict__ KV,  // [16384][2048]
                         unsigned short* __restrict__ VTb) {
  __shared__ unsigned short tile[256 * 66];    // [key][d], padded
  int bch = blockIdx.x;
  int hh = bch & 15, c = (bch >> 4) & 15, b = bch >> 8;
  size_t kvbase = (size_t)b * 4096 + (size_t)c * 256;
  int t = threadIdx.x;
#pragma unroll
  for (int it = 0; it < 16; ++it) {
    int flat = it * 256 + t;          // 0..4095 uint2
    int row = flat >> 4, cu = flat & 15;
    uint2 v = *(const uint2*)(KV + (kvbase + row) * 2048 + 1024 + hh * 64 + cu * 4);
    int d0 = cu * 4;
    tile[row * 66 + d0 + 0] = (unsigned short)(v.x & 0xffff);
    tile[row * 66 + d0 + 1] = (unsigned short)(v.x >> 16);
    tile[row * 66 + d0 + 2] = (unsigned short)(v.y & 0xffff);
    tile[row * 66 + d0 + 3] = (unsigned short)(v.y >> 16);
  }
  __syncthreads();
  unsigned short* dst = VTb + (size_t)bch * 16384;
#pragma unroll
  for (int it = 0; it < 16; ++it) {
    int flat = it * 256 + t;          // 0..4095 uint2
    int d = flat >> 6, ju = flat & 63;
    int j = ju * 4;
    unsigned int lo = (unsigned int)tile[(j + 0) * 66 + d] |
                      ((unsigned int)tile[(j + 1) * 66 + d] << 16);
    unsigned int hi = (unsigned int)tile[(j + 2) * 66 + d] |
                      ((unsigned int)tile[(j + 3) * 66 + d] << 16);
    int u = j >> 3, joff = j & 7;
    int phys = d * 256 + ((u ^ (d & 7)) << 3) + joff;
    uint2 o; o.x = lo; o.y = hi;
    *(uint2*)(dst + phys) = o;
  }
}

// ---------------- attention: one block per (b, c, head), 2 blocks/CU --------
__launch_bounds__(256, 2)
__global__ void cca_attn_k(const unsigned short* __restrict__ Q,   // [4096][1024]
                           const unsigned short* __restrict__ KV,  // [16384][2048]
                           const unsigned short* __restrict__ VTb, // per-bch 64x256 swz
                           unsigned short* __restrict__ O) {       // [4096][1024]
  __shared__ unsigned short smemA[64 * 64 + 256 * 64];
  __shared__ unsigned short VTlds[64 * 256];
  unsigned short* Qsh = smemA;
  unsigned short* Ksh = smemA + 64 * 64;
  unsigned short* Psh = smemA;                // alias (post-barrier)
  int bch = blockIdx.x;
  int hh = bch & 15, c = (bch >> 4) & 15, b = bch >> 8;
  int t = threadIdx.x, lane = t & 63, wv = t >> 6;
  int l15 = lane & 15, quad = lane >> 4;
  size_t qbase = (size_t)b * 1024 + (size_t)c * 64;
  size_t kvbase = (size_t)b * 4096 + (size_t)c * 256;
  int hoff = hh * 64;

  {
    int rowi = lane >> 3, chk = lane & 7;
#pragma unroll
    for (int ii = 0; ii < 2; ++ii) {
      int seg = wv + ii * 4;
      int row = seg * 8 + rowi;
      gl2lds16(Q + (qbase + row) * 1024 + hoff + chk * 8, Qsh + seg * 512);
    }
#pragma unroll
    for (int ii = 0; ii < 8; ++ii) {
      int seg = wv + ii * 4;
      int row = seg * 8 + rowi;
      gl2lds16(KV + (kvbase + row) * 2048 + hoff + chk * 8, Ksh + seg * 512);
    }
    const unsigned short* vsrc = VTb + (size_t)bch * 16384;
#pragma unroll
    for (int ii = 0; ii < 8; ++ii) {
      int seg = wv + ii * 4;
      gl2lds16(vsrc + seg * 512 + lane * 8, VTlds + seg * 512);
    }
  }
  __syncthreads();

  floatx4 st[16];
#pragma unroll
  for (int i = 0; i < 16; ++i) st[i] = zero4();
  bf16x8 a0 = *(const bf16x8*)&Qsh[(wv * 16 + l15) * 64 + quad * 8];
  bf16x8 a1 = *(const bf16x8*)&Qsh[(wv * 16 + l15) * 64 + 32 + quad * 8];
#pragma unroll
  for (int kt = 0; kt < 16; ++kt) {
    bf16x8 b0 = *(const bf16x8*)&Ksh[(kt * 16 + l15) * 64 + quad * 8];
    bf16x8 b1 = *(const bf16x8*)&Ksh[(kt * 16 + l15) * 64 + 32 + quad * 8];
    st[kt] = __builtin_amdgcn_mfma_f32_16x16x32_bf16(a0, b0, st[kt], 0, 0, 0);
    st[kt] = __builtin_amdgcn_mfma_f32_16x16x32_bf16(a1, b1, st[kt], 0, 0, 0);
  }
  __syncthreads();   // Qsh/Ksh dead; Psh may alias

  const float scale = 0.125f;  // 1/sqrt(64)
#pragma unroll
  for (int r = 0; r < 4; ++r) {
    float mx = -1e30f;
#pragma unroll
    for (int kt = 0; kt < 16; ++kt) mx = fmaxf(mx, st[kt][r]);
    mx = fmaxf(mx, __shfl_xor(mx, 1));
    mx = fmaxf(mx, __shfl_xor(mx, 2));
    mx = fmaxf(mx, __shfl_xor(mx, 4));
    mx = fmaxf(mx, __shfl_xor(mx, 8));
    float sum = 0.f;
#pragma unroll
    for (int kt = 0; kt < 16; ++kt) {
      float e = __expf((st[kt][r] - mx) * scale);
      st[kt][r] = e;
      sum += e;
    }
    sum += __shfl_xor(sum, 1);
    sum += __shfl_xor(sum, 2);
    sum += __shfl_xor(sum, 4);
    sum += __shfl_xor(sum, 8);
    float inv = 1.0f / sum;
    int prow = wv * 16 + quad * 4 + r;
#pragma unroll
    for (int kt = 0; kt < 16; ++kt)
      Psh[prow * 264 + kt * 16 + l15] = (unsigned short)f2bf(st[kt][r] * inv);
  }

  floatx4 ot[4];
#pragma unroll
  for (int nt = 0; nt < 4; ++nt) ot[nt] = zero4();
#pragma unroll
  for (int kt2 = 0; kt2 < 8; ++kt2) {
    bf16x8 ap = *(const bf16x8*)&Psh[(wv * 16 + l15) * 264 + kt2 * 32 + quad * 8];
#pragma unroll
    for (int nt = 0; nt < 4; ++nt) {
      int vrow = nt * 16 + l15;
      int u = kt2 * 4 + quad;
      bf16x8 bv8 = *(const bf16x8*)&VTlds[vrow * 256 + ((u ^ (vrow & 7)) << 3)];
      ot[nt] = __builtin_amdgcn_mfma_f32_16x16x32_bf16(ap, bv8, ot[nt], 0, 0, 0);
    }
  }
#pragma unroll
  for (int nt = 0; nt < 4; ++nt) {
#pragma unroll
    for (int r = 0; r < 4; ++r) {
      int i = wv * 16 + quad * 4 + r;
      int dcol = hoff + nt * 16 + l15;
      O[(qbase + i) * 1024 + dcol] = (unsigned short)f2bf(ot[nt][r]);
    }
  }
}

extern "C" void kernel_launch(void* const* d_in, const int* in_sizes, int n_in,
                              void* d_out, int out_size, void* d_ws, size_t ws_size,
                              hipStream_t stream) {
  const float* h  = (const float*)d_in[0];
  const float* e  = (const float*)d_in[1];
  const float* g  = (const float*)d_in[2];
  const float* Wq = (const float*)d_in[3];
  const float* bq = (const float*)d_in[4];
  const float* Wk = (const float*)d_in[5];
  const float* bk = (const float*)d_in[6];
  const float* Wv = (const float*)d_in[7];
  const float* bv = (const float*)d_in[8];
  const float* Wo = (const float*)d_in[9];
  const float* bo = (const float*)d_in[10];
  float* out = (float*)d_out;

  unsigned short* ws   = (unsigned short*)d_ws;
  unsigned short* hn   = ws;                                   // 4096*1024
  unsigned short* WqT  = hn   + (size_t)4096 * 1024;           // 1024*1024
  unsigned short* WkvT = WqT  + (size_t)1024 * 1024;           // 2048*1024
  unsigned short* WoT  = WkvT + (size_t)2048 * 1024;           // 1024*1024
  unsigned short* Qb   = WoT  + (size_t)1024 * 1024;           // 4096*1024
  unsigned short* KVb  = Qb   + (size_t)4096 * 1024;           // 16384*2048
  unsigned short* Ob   = KVb  + (size_t)16384 * 2048;          // 4096*1024
  unsigned short* eb   = Ob   + (size_t)4096 * 1024;           // 16384*1024
  unsigned short* VTb  = eb;   // alias: eb dead after QKV GEMM dispatch

  cca_prep_k<<<21756, 256, 0, stream>>>(
      Wq, Wk, Wv, Wo, WqT, WkvT, WkvT + (size_t)1024 * 1024, WoT,
      e, eb, h, g, hn, out);

  cca_gemmQKV_k<<<2304, 256, 0, stream>>>(eb, WkvT, bk, bv, KVb,
                                          hn, WqT, bq, Qb);

  cca_vt_k<<<1024, 256, 0, stream>>>(KVb, VTb);

  cca_attn_k<<<1024, 256, 0, stream>>>(Qb, KVb, VTb, Ob);

  cca_gemmO_k<<<dim3(32, 16), 256, 0, stream>>>(Ob, WoT, bo, h, out);
}